// Round 20
// baseline (53.023 us; speedup 1.0000x reference)
//
#include <hip/hip_runtime.h>

// speed[n,d] = sum_{f,m} Cont[f] * exp(-||P[n]-S[f,m]||^2) * V[f,m,d]
//
// Two chained MFMAs per 32x32-tile (layouts validated R7-R9):
//  MFMA1: D1[e][n] = -K1*d2(n,e)  (A=support frag, B=point frag)
//  fused: b2 dword m = bf16pack(w(D1[2m]), w(D1[2m+1]))
//  MFMA2: D2[d][n] += cv[d][e] * w[e][n], acc carried in C across tiles.
// R20 = R18 (LDS staging, 42.1us) + PIPE-BALANCED exp: the trans pipe is
// the binder (~14 cyc/wave-exp x 16/tile = 224 cyc vs 40 VALU). Move 6 of
// 16 exps to the VALU via branch-free bit-trick exp2:
//   t = x + 1.5*2^23 (RNE to int in mantissa); r = x - (t-MG) in [-.5,.5];
//   p = deg-3 Taylor(r); result_bits = bits(p) + (bits(t)<<23)
// (low 9 bits of 0x4B400000 are 0 -> shift cancels the magic; x clamped
// >= -120 keeps exponent normal). No ldexp/cvt (R12's poly died there).
// New balance: trans 10x14=140, VALU 40+6x20=160 (was 224 trans-bound).
// R15-R19 lessons: occupancy-, ILP-, prefetch-invariant at 42-46us ->
// only pipe rebalancing is left.
// Staging (uniform 784B tile stride): [half0 32x16B | half1 32x8B | const 8B]
// ws: stage 128*784=100,352 | A2 24,576 -> 124,928 <= 128K proven budget.

typedef short  bf16x8 __attribute__((ext_vector_type(8)));
typedef float  f32x16 __attribute__((ext_vector_type(16)));

#define K1f 1.4426950408889634f
#define K2f 2.8853900817779268f

constexpr int N_PTS  = 65536;
constexpr int FM     = 4096;
constexpr int SPLITS = 8;
constexpr int ETILES = FM / 32;          // 128 tiles
constexpr int TPS    = ETILES / SPLITS;  // 16 tiles per block
constexpr int TSTRIDE = 784;
constexpr size_t A2_OFF = (size_t)ETILES * TSTRIDE;      // 100,352
constexpr int BLK    = 512;              // 8 waves per block (R15 best)
constexpr int PTS_PER_BLK = 256;
constexpr int STAGE_U4 = TPS * TSTRIDE / 16;   // 784 uint4 (12,544 B)
constexpr int A2_U4    = TPS * 192 / 16;       // 192 uint4 ( 3,072 B)
constexpr int LDS_A2_OFF = TPS * TSTRIDE;      // 12,544

__device__ __forceinline__ unsigned short bf16r(float f) {   // RNE f32->bf16
  unsigned u = __float_as_uint(f);
  return (unsigned short)((u + 0x7FFFu + ((u >> 16) & 1u)) >> 16);
}
__device__ __forceinline__ float bf2f(unsigned short h) {
  return __uint_as_float(((unsigned)h) << 16);
}

// Branch-free exp2 on the FULL-RATE VALU pipe (no trans, no cvt, no ldexp):
__device__ __forceinline__ float exp2p(float x) {
  x = fmaxf(x, -120.0f);               // keep 2^n in normal range
  float t = x + 12582912.0f;           // RNE round-to-int via magic
  float r = x - (t - 12582912.0f);     // r in [-0.5, 0.5]
  float p = fmaf(r, 0.055504109f, 0.240226507f);
  p = fmaf(p, r, 0.693147181f);
  p = fmaf(p, r, 1.0f);                // ~2^r, rel err ~6e-4 << bf16 ulp
  return __uint_as_float(__float_as_uint(p) + (__float_as_uint(t) << 23));
}

union FragU { uint4 u4; bf16x8 bf; };

__global__ __launch_bounds__(256) void pack_kernel(
    const float* __restrict__ supp_pts, const float* __restrict__ supp_vec,
    const float* __restrict__ Cont, char* __restrict__ ws) {
  int e = blockIdx.x * blockDim.x + threadIdx.x;
  if (e >= FM) return;
  float sx = supp_pts[e * 3 + 0];
  float sy = supp_pts[e * 3 + 1];
  float sz = supp_pts[e * 3 + 2];
  float tx = K2f * sx, ty = K2f * sy, tz = K2f * sz;
  unsigned short shx = bf16r(tx), shy = bf16r(ty), shz = bf16r(tz);
  unsigned short slx = bf16r(tx - bf2f(shx));
  unsigned short sly = bf16r(ty - bf2f(shy));
  unsigned short slz = bf16r(tz - bf2f(shz));
  float ye = -K1f * (sx * sx + sy * sy + sz * sz);
  unsigned short yh = bf16r(ye);
  unsigned short yl = bf16r(ye - bf2f(yh));
  const unsigned short ONE = 0x3F80;    // bf16 1.0

  int t = e >> 5, c = e & 31;
  char* tb = ws + (size_t)t * TSTRIDE;
  // half0 fragment, 16B: [shx,shy,shz,shx,shy,shz,slx,sly]
  unsigned short* pa = (unsigned short*)(tb) + (size_t)c * 8;
  pa[0] = shx; pa[1] = shy; pa[2] = shz; pa[3] = shx;
  pa[4] = shy; pa[5] = shz; pa[6] = slx; pa[7] = sly;
  // half1 compact, 8B: [slz, yh, yl, 0]
  unsigned short* pb = (unsigned short*)(tb + 512) + (size_t)c * 4;
  pb[0] = slz; pb[1] = yh; pb[2] = yl; pb[3] = 0;
  // per-tile const pair, 8B: [ONE, ONE, 0, 0]
  if (c == 0) {
    unsigned short* pc = (unsigned short*)(tb + 768);
    pc[0] = ONE; pc[1] = ONE; pc[2] = 0; pc[3] = 0;
  }

  // A2: cv[d][e] at slot (t, frag, h, d, j), e = (j&3)+8*(j>>2)+4h+16*frag
  int f = e >> 9;
  float cf = Cont[f];
  unsigned short cv0 = bf16r(cf * supp_vec[e * 3 + 0]);
  unsigned short cv1 = bf16r(cf * supp_vec[e * 3 + 1]);
  unsigned short cv2 = bf16r(cf * supp_vec[e * 3 + 2]);
  int frag = (c >> 4) & 1, el16 = c & 15;
  int h = (el16 >> 2) & 1;
  int j = (el16 & 3) + 4 * (el16 >> 3);
  unsigned short* a2 = (unsigned short*)(ws + A2_OFF) +
                       (size_t)(((t * 2 + frag) * 2 + h) * 24 + j);
  a2[0] = cv0; a2[8] = cv1; a2[16] = cv2;   // row stride 8 slots
}

__global__ __launch_bounds__(BLK) void speed_kernel(
    const float* __restrict__ Points, const char* __restrict__ ws,
    float* __restrict__ out) {
  __shared__ uint4 lds_u4[STAGE_U4 + A2_U4];   // 15,616 B

  const int tid   = threadIdx.x;
  const int l     = tid & 63;
  const int wave  = tid >> 6;               // 0..7
  const int half  = l >> 5;
  const int c     = l & 31;
  const int split = blockIdx.x & (SPLITS - 1);
  const int nblk  = blockIdx.x / SPLITS;
  const int n_base = nblk * PTS_PER_BLK + wave * 32;
  const int tbase  = split * TPS;

  // ---- cooperative bulk stage: global -> LDS (one pass, overlapped) ----
  {
    const uint4* g1 = (const uint4*)(ws + (size_t)tbase * TSTRIDE);
    const uint4* g2 = (const uint4*)(ws + A2_OFF + (size_t)tbase * 192);
#pragma unroll
    for (int i = tid; i < STAGE_U4; i += BLK) lds_u4[i] = g1[i];
    if (tid < A2_U4) lds_u4[STAGE_U4 + tid] = g2[tid];
  }

  // ---- point fragment (B operand of MFMA1) ----
  const int n = n_base + c;
  float x = Points[n * 3 + 0];
  float y = Points[n * 3 + 1];
  float z = Points[n * 3 + 2];
  float e1 = -K1f * (x * x + y * y + z * z);
  unsigned short qhx = bf16r(x), qhy = bf16r(y), qhz = bf16r(z);
  unsigned short qlx = bf16r(x - bf2f(qhx));
  unsigned short qly = bf16r(y - bf2f(qhy));
  unsigned short qlz = bf16r(z - bf2f(qhz));
  unsigned short xh  = bf16r(e1);
  unsigned short xl  = bf16r(e1 - bf2f(xh));
  const short ONE = (short)0x3F80;

  bf16x8 af;
  if (half == 0) {
    af = (bf16x8){(short)qhx, (short)qhy, (short)qhz, (short)qlx,
                  (short)qly, (short)qlz, (short)qhx, (short)qhy};
  } else {
    af = (bf16x8){(short)qhz, ONE, ONE, 0, (short)xh, (short)xl, 0, 0};
  }

  __syncthreads();

  // ---- branchless per-lane LDS pointers, 784B tile stride ----
  const char* lds = (const char*)lds_u4;
  const char* pLo  = (half == 0) ? lds + (size_t)c * 16
                                 : lds + 512 + (size_t)c * 8;
  const char* pHi  = (half == 0) ? lds + (size_t)c * 16 + 8
                                 : lds + 768;
  const uint4* pA2 = (const uint4*)(lds + LDS_A2_OFF) +
                     (half * 3 + (c < 2 ? c : 2));

  f32x16 acc2 = {};
  const f32x16 zc = {};

// trans-pipe exp pair -> packed bf16 dword
#define PACK2T(r0, r1)                                                       \
  __builtin_amdgcn_perm(                                                     \
      __float_as_uint(__builtin_amdgcn_exp2f(D1[r1])),                       \
      __float_as_uint(__builtin_amdgcn_exp2f(D1[r0])), 0x07060302u)
// VALU-pipe exp pair -> packed bf16 dword
#define PACK2P(r0, r1)                                                       \
  __builtin_amdgcn_perm(__float_as_uint(exp2p(D1[r1])),                      \
                        __float_as_uint(exp2p(D1[r0])), 0x07060302u)

#pragma unroll 4
  for (int t = 0; t < TPS; ++t) {
    uint2 lo = *(const uint2*)(pLo + (size_t)t * TSTRIDE);
    uint2 hi = *(const uint2*)(pHi + (size_t)t * TSTRIDE);
    FragU fa;  fa.u4  = make_uint4(lo.x, lo.y, hi.x, hi.y);
    FragU a2a; a2a.u4 = pA2[(size_t)t * 12];
    FragU a2b; a2b.u4 = pA2[(size_t)t * 12 + 6];

    f32x16 D1 = __builtin_amdgcn_mfma_f32_32x32x16_bf16(fa.bf, af, zc, 0, 0, 0);

    // 10 exps on trans pipe, 6 on VALU pipe (pipe balance ~140 vs ~160 cyc)
    FragU b2a;
    b2a.u4 = make_uint4(PACK2T(0, 1), PACK2T(2, 3), PACK2T(4, 5), PACK2T(6, 7));
    acc2 = __builtin_amdgcn_mfma_f32_32x32x16_bf16(a2a.bf, b2a.bf, acc2, 0, 0, 0);

    FragU b2b;
    b2b.u4 = make_uint4(PACK2T(8, 9), PACK2P(10, 11), PACK2P(12, 13),
                        PACK2P(14, 15));
    acc2 = __builtin_amdgcn_mfma_f32_32x32x16_bf16(a2b.bf, b2b.bf, acc2, 0, 0, 0);
  }
#undef PACK2T
#undef PACK2P

  // D2 rows 0..2 (= d) live at half 0, regs 0..2; col = n = lane&31.
  if (half == 0) {
    const int nn = n_base + c;
    unsafeAtomicAdd(&out[nn * 3 + 0], acc2[0]);
    unsafeAtomicAdd(&out[nn * 3 + 1], acc2[1]);
    unsafeAtomicAdd(&out[nn * 3 + 2], acc2[2]);
  }
}

extern "C" void kernel_launch(void* const* d_in, const int* in_sizes, int n_in,
                              void* d_out, int out_size, void* d_ws, size_t ws_size,
                              hipStream_t stream) {
  const float* Points   = (const float*)d_in[0];
  const float* supp_pts = (const float*)d_in[1];
  const float* supp_vec = (const float*)d_in[2];
  const float* Cont     = (const float*)d_in[3];
  float* out = (float*)d_out;
  char* ws = (char*)d_ws;    // 124,928 B used (<=128K proven budget)

  (void)hipMemsetAsync(d_out, 0, (size_t)out_size * sizeof(float), stream);
  pack_kernel<<<FM / 256, 256, 0, stream>>>(supp_pts, supp_vec, Cont, ws);
  speed_kernel<<<(N_PTS / PTS_PER_BLK) * SPLITS, BLK, 0, stream>>>(Points, ws, out);
}

// Round 21
// 40.342 us; speedup vs baseline: 1.3143x; 1.3143x over previous
//
#include <hip/hip_runtime.h>

// speed[n,d] = sum_{f,m} Cont[f] * exp(-||P[n]-S[f,m]||^2) * V[f,m,d]
//
// Two chained MFMAs per 32x32-tile (layouts validated R7-R9):
//  MFMA1: D1[e][n] = -K1*d2(n,e)  (A=support frag, B=point frag)
//  fused: b2 dword m = bf16pack(exp2(D1[2m]), exp2(D1[2m+1]))
//  MFMA2: D2[d][n] += cv[d][e] * w[e][n], acc carried in C across tiles.
// R21 = R19 (LDS staging + dual e-tile, 42.07us) + memset folded into
// pack_kernel (grid-stride zero of d_out) -> 2 dispatches instead of 3.
// FINAL MODEL: binder is the trans pipe (v_exp_f32 ~16cyc/wave-op pipe
// occupancy; 16/tile = 256 cyc vs 118 VALU issue). 4.19M wave-exps are
// algorithmically irreducible -> ~27us in-kernel floor; measured ~38 =
// 72% trans utilization, invariant to occupancy/ILP/prefetch (R14-R19).
// R20: VALU-poly exp costs ~43cyc/exp issued (VALUBusy 45->86%) - dead.
// R12/R20 lesson: v_exp_f32 is the cheapest exp on this HW. Keep it.
// Staging (uniform 784B tile stride): [half0 32x16B | half1 32x8B | const 8B]
// ws: stage 128*784=100,352 | A2 24,576 -> 124,928 <= 128K proven budget.

typedef short  bf16x8 __attribute__((ext_vector_type(8)));
typedef float  f32x16 __attribute__((ext_vector_type(16)));

#define K1f 1.4426950408889634f
#define K2f 2.8853900817779268f

constexpr int N_PTS  = 65536;
constexpr int FM     = 4096;
constexpr int SPLITS = 8;
constexpr int ETILES = FM / 32;          // 128 tiles
constexpr int TPS    = ETILES / SPLITS;  // 16 tiles per block
constexpr int TSTRIDE = 784;
constexpr size_t A2_OFF = (size_t)ETILES * TSTRIDE;      // 100,352
constexpr int BLK    = 512;              // 8 waves per block (R15 best)
constexpr int PTS_PER_BLK = 256;
constexpr int STAGE_U4 = TPS * TSTRIDE / 16;   // 784 uint4 (12,544 B)
constexpr int A2_U4    = TPS * 192 / 16;       // 192 uint4 ( 3,072 B)
constexpr int LDS_A2_OFF = TPS * TSTRIDE;      // 12,544
constexpr int OUT_U4 = N_PTS * 3 * 4 / 16;     // 49,152 uint4 of output

__device__ __forceinline__ unsigned short bf16r(float f) {   // RNE f32->bf16
  unsigned u = __float_as_uint(f);
  return (unsigned short)((u + 0x7FFFu + ((u >> 16) & 1u)) >> 16);
}
__device__ __forceinline__ float bf2f(unsigned short h) {
  return __uint_as_float(((unsigned)h) << 16);
}

union FragU { uint4 u4; bf16x8 bf; };

__global__ __launch_bounds__(256) void pack_kernel(
    const float* __restrict__ supp_pts, const float* __restrict__ supp_vec,
    const float* __restrict__ Cont, char* __restrict__ ws,
    uint4* __restrict__ out_u4) {
  int e = blockIdx.x * blockDim.x + threadIdx.x;
  if (e >= FM) return;

  // ---- zero d_out (replaces the hipMemsetAsync dispatch) ----
  {
    const uint4 z = make_uint4(0u, 0u, 0u, 0u);
#pragma unroll
    for (int i = 0; i < OUT_U4 / FM; ++i)        // 12 stores per thread
      out_u4[e + i * FM] = z;
  }

  float sx = supp_pts[e * 3 + 0];
  float sy = supp_pts[e * 3 + 1];
  float sz = supp_pts[e * 3 + 2];
  float tx = K2f * sx, ty = K2f * sy, tz = K2f * sz;
  unsigned short shx = bf16r(tx), shy = bf16r(ty), shz = bf16r(tz);
  unsigned short slx = bf16r(tx - bf2f(shx));
  unsigned short sly = bf16r(ty - bf2f(shy));
  unsigned short slz = bf16r(tz - bf2f(shz));
  float ye = -K1f * (sx * sx + sy * sy + sz * sz);
  unsigned short yh = bf16r(ye);
  unsigned short yl = bf16r(ye - bf2f(yh));
  const unsigned short ONE = 0x3F80;    // bf16 1.0

  int t = e >> 5, c = e & 31;
  char* tb = ws + (size_t)t * TSTRIDE;
  // half0 fragment, 16B: [shx,shy,shz,shx,shy,shz,slx,sly]
  unsigned short* pa = (unsigned short*)(tb) + (size_t)c * 8;
  pa[0] = shx; pa[1] = shy; pa[2] = shz; pa[3] = shx;
  pa[4] = shy; pa[5] = shz; pa[6] = slx; pa[7] = sly;
  // half1 compact, 8B: [slz, yh, yl, 0]
  unsigned short* pb = (unsigned short*)(tb + 512) + (size_t)c * 4;
  pb[0] = slz; pb[1] = yh; pb[2] = yl; pb[3] = 0;
  // per-tile const pair, 8B: [ONE, ONE, 0, 0]
  if (c == 0) {
    unsigned short* pc = (unsigned short*)(tb + 768);
    pc[0] = ONE; pc[1] = ONE; pc[2] = 0; pc[3] = 0;
  }

  // A2: cv[d][e] at slot (t, frag, h, d, j), e = (j&3)+8*(j>>2)+4h+16*frag
  int f = e >> 9;
  float cf = Cont[f];
  unsigned short cv0 = bf16r(cf * supp_vec[e * 3 + 0]);
  unsigned short cv1 = bf16r(cf * supp_vec[e * 3 + 1]);
  unsigned short cv2 = bf16r(cf * supp_vec[e * 3 + 2]);
  int frag = (c >> 4) & 1, el16 = c & 15;
  int h = (el16 >> 2) & 1;
  int j = (el16 & 3) + 4 * (el16 >> 3);
  unsigned short* a2 = (unsigned short*)(ws + A2_OFF) +
                       (size_t)(((t * 2 + frag) * 2 + h) * 24 + j);
  a2[0] = cv0; a2[8] = cv1; a2[16] = cv2;   // row stride 8 slots
}

__global__ __launch_bounds__(BLK) void speed_kernel(
    const float* __restrict__ Points, const char* __restrict__ ws,
    float* __restrict__ out) {
  __shared__ uint4 lds_u4[STAGE_U4 + A2_U4];   // 15,616 B

  const int tid   = threadIdx.x;
  const int l     = tid & 63;
  const int wave  = tid >> 6;               // 0..7
  const int half  = l >> 5;
  const int c     = l & 31;
  const int split = blockIdx.x & (SPLITS - 1);
  const int nblk  = blockIdx.x / SPLITS;
  const int n_base = nblk * PTS_PER_BLK + wave * 32;
  const int tbase  = split * TPS;

  // ---- cooperative bulk stage: global -> LDS (one pass, overlapped) ----
  {
    const uint4* g1 = (const uint4*)(ws + (size_t)tbase * TSTRIDE);
    const uint4* g2 = (const uint4*)(ws + A2_OFF + (size_t)tbase * 192);
#pragma unroll
    for (int i = tid; i < STAGE_U4; i += BLK) lds_u4[i] = g1[i];
    if (tid < A2_U4) lds_u4[STAGE_U4 + tid] = g2[tid];
  }

  // ---- point fragment (B operand of MFMA1) ----
  const int n = n_base + c;
  float x = Points[n * 3 + 0];
  float y = Points[n * 3 + 1];
  float z = Points[n * 3 + 2];
  float e1 = -K1f * (x * x + y * y + z * z);
  unsigned short qhx = bf16r(x), qhy = bf16r(y), qhz = bf16r(z);
  unsigned short qlx = bf16r(x - bf2f(qhx));
  unsigned short qly = bf16r(y - bf2f(qhy));
  unsigned short qlz = bf16r(z - bf2f(qhz));
  unsigned short xh  = bf16r(e1);
  unsigned short xl  = bf16r(e1 - bf2f(xh));
  const short ONE = (short)0x3F80;

  bf16x8 af;
  if (half == 0) {
    af = (bf16x8){(short)qhx, (short)qhy, (short)qhz, (short)qlx,
                  (short)qly, (short)qlz, (short)qhx, (short)qhy};
  } else {
    af = (bf16x8){(short)qhz, ONE, ONE, 0, (short)xh, (short)xl, 0, 0};
  }

  __syncthreads();

  // ---- branchless per-lane LDS pointers, 784B tile stride ----
  const char* lds = (const char*)lds_u4;
  const char* pLo  = (half == 0) ? lds + (size_t)c * 16
                                 : lds + 512 + (size_t)c * 8;
  const char* pHi  = (half == 0) ? lds + (size_t)c * 16 + 8
                                 : lds + 768;
  const uint4* pA2 = (const uint4*)(lds + LDS_A2_OFF) +
                     (half * 3 + (c < 2 ? c : 2));

  f32x16 acc2 = {};
  const f32x16 zc = {};

#define PACK2(D, r0, r1)                                                     \
  __builtin_amdgcn_perm(                                                     \
      __float_as_uint(__builtin_amdgcn_exp2f(D[r1])),                        \
      __float_as_uint(__builtin_amdgcn_exp2f(D[r0])), 0x07060302u)

#define CONSUME(D, A2A, A2B)                                                 \
  {                                                                          \
    FragU b2a;                                                               \
    b2a.u4 = make_uint4(PACK2(D, 0, 1), PACK2(D, 2, 3),                      \
                        PACK2(D, 4, 5), PACK2(D, 6, 7));                     \
    acc2 = __builtin_amdgcn_mfma_f32_32x32x16_bf16(A2A.bf, b2a.bf, acc2,     \
                                                   0, 0, 0);                 \
    FragU b2b;                                                               \
    b2b.u4 = make_uint4(PACK2(D, 8, 9), PACK2(D, 10, 11),                    \
                        PACK2(D, 12, 13), PACK2(D, 14, 15));                 \
    acc2 = __builtin_amdgcn_mfma_f32_32x32x16_bf16(A2B.bf, b2b.bf, acc2,     \
                                                   0, 0, 0);                 \
  }

#pragma unroll 2
  for (int t = 0; t < TPS; t += 2) {
    // dual e-tile: two independent D1 chains share af and acc2
    uint2 lo0 = *(const uint2*)(pLo + (size_t)t * TSTRIDE);
    uint2 hi0 = *(const uint2*)(pHi + (size_t)t * TSTRIDE);
    uint2 lo1 = *(const uint2*)(pLo + (size_t)(t + 1) * TSTRIDE);
    uint2 hi1 = *(const uint2*)(pHi + (size_t)(t + 1) * TSTRIDE);
    FragU fa0, fa1;
    fa0.u4 = make_uint4(lo0.x, lo0.y, hi0.x, hi0.y);
    fa1.u4 = make_uint4(lo1.x, lo1.y, hi1.x, hi1.y);
    FragU a2a0, a2b0, a2a1, a2b1;
    a2a0.u4 = pA2[(size_t)t * 12];
    a2b0.u4 = pA2[(size_t)t * 12 + 6];
    a2a1.u4 = pA2[(size_t)(t + 1) * 12];
    a2b1.u4 = pA2[(size_t)(t + 1) * 12 + 6];

    f32x16 D1a = __builtin_amdgcn_mfma_f32_32x32x16_bf16(fa0.bf, af, zc, 0, 0, 0);
    f32x16 D1b = __builtin_amdgcn_mfma_f32_32x32x16_bf16(fa1.bf, af, zc, 0, 0, 0);

    CONSUME(D1a, a2a0, a2b0);
    CONSUME(D1b, a2a1, a2b1);
  }
#undef CONSUME
#undef PACK2

  // D2 rows 0..2 (= d) live at half 0, regs 0..2; col = n = lane&31.
  if (half == 0) {
    const int nn = n_base + c;
    unsafeAtomicAdd(&out[nn * 3 + 0], acc2[0]);
    unsafeAtomicAdd(&out[nn * 3 + 1], acc2[1]);
    unsafeAtomicAdd(&out[nn * 3 + 2], acc2[2]);
  }
}

extern "C" void kernel_launch(void* const* d_in, const int* in_sizes, int n_in,
                              void* d_out, int out_size, void* d_ws, size_t ws_size,
                              hipStream_t stream) {
  const float* Points   = (const float*)d_in[0];
  const float* supp_pts = (const float*)d_in[1];
  const float* supp_vec = (const float*)d_in[2];
  const float* Cont     = (const float*)d_in[3];
  float* out = (float*)d_out;
  char* ws = (char*)d_ws;    // 124,928 B used (<=128K proven budget)

  pack_kernel<<<FM / 256, 256, 0, stream>>>(supp_pts, supp_vec, Cont, ws,
                                            (uint4*)d_out);
  speed_kernel<<<(N_PTS / PTS_PER_BLK) * SPLITS, BLK, 0, stream>>>(Points, ws, out);
}